// Round 1
// baseline (588.142 us; speedup 1.0000x reference)
//
#include <hip/hip_runtime.h>
#include <hip/hip_bf16.h>

#define BB   16
#define EMB  768
#define CIN  64
#define COUT 64
#define KK   3
#define HH   112
#define WW   112
#define HID  192                    // EMB/4
#define TOTAL (COUT*CIN*KK*KK)      // 36864
#define KSZ  (CIN*KK*KK)            // 576 per output channel

// ---------------- Kernel A: h = relu(cls @ W1 + b1)  (16 x 192) ----------------
__global__ void mlp1_kernel(const float* __restrict__ cls, const float* __restrict__ W1,
                            const float* __restrict__ b1, float* __restrict__ h) {
    __shared__ float xs[EMB];
    const int b = blockIdx.x;
    const int j = threadIdx.x;                 // 0..191
    for (int k = j; k < EMB; k += HID) xs[k] = cls[b * EMB + k];
    __syncthreads();
    float acc = b1[j];
    #pragma unroll 8
    for (int k = 0; k < EMB; ++k) acc += xs[k] * W1[k * HID + j];
    h[b * HID + j] = fmaxf(acc, 0.f);
}

// ---------------- Kernel B: params = tanh(h @ W2 + b2)  (16 x 36864) ----------------
__global__ __launch_bounds__(256) void mlp2_kernel(const float* __restrict__ h,
                                                   const float* __restrict__ W2,
                                                   const float* __restrict__ b2,
                                                   float* __restrict__ params) {
    __shared__ float hs[BB * HID];
    const int tid = threadIdx.x;
    for (int i = tid; i < BB * HID; i += 256) hs[i] = h[i];
    __syncthreads();
    const int t = blockIdx.x * 256 + tid;      // 0..36863 (grid = 144 exact)
    float acc[BB];
    const float bias = b2[t];
    #pragma unroll
    for (int b = 0; b < BB; ++b) acc[b] = bias;
    for (int k = 0; k < HID; ++k) {
        const float w = W2[k * TOTAL + t];
        #pragma unroll
        for (int b = 0; b < BB; ++b) acc[b] += hs[b * HID + k] * w;
    }
    #pragma unroll
    for (int b = 0; b < BB; ++b) params[b * TOTAL + t] = tanhf(acc[b]);
}

// ---------------- Kernel C: per-sample conv (SAME, 3x3) + residual ----------------
// Block: 256 threads as 16(ty) x 16(tx); each thread -> 7 consecutive x pixels, 8 co.
// Tile: 16 rows x 112 cols (full width). Grid: (7 row-tiles, 8 co-groups, 16 batch).
#define CO_PB 8
#define TR    16
#define PX    7
#define TCOLS 114                  // cols -1 .. 112
#define TROWS 18                   // rows y0-1 .. y0+16

__global__ __launch_bounds__(256) void conv_kernel(const float* __restrict__ feat,
                                                   const float* __restrict__ params,
                                                   float* __restrict__ out) {
    __shared__ float ks[CO_PB * KSZ];          // 18432 B
    __shared__ float ts[TROWS * TCOLS];        //  8208 B
    const int tile = blockIdx.x;               // 0..6
    const int cog  = blockIdx.y;               // 0..7
    const int b    = blockIdx.z;               // 0..15
    const int tid  = threadIdx.x;
    const int ty   = tid >> 4;
    const int tx   = tid & 15;
    const int y0   = tile * TR;

    // stage the 8 per-sample kernels for this co-group
    const float* kp = params + (size_t)b * TOTAL + (size_t)cog * CO_PB * KSZ;
    for (int i = tid; i < CO_PB * KSZ; i += 256) ks[i] = kp[i];

    float acc[CO_PB][PX];
    #pragma unroll
    for (int o = 0; o < CO_PB; ++o)
        #pragma unroll
        for (int p = 0; p < PX; ++p) acc[o][p] = 0.f;

    const float* fb = feat + (size_t)b * CIN * HH * WW;

    for (int ci = 0; ci < CIN; ++ci) {
        __syncthreads();
        // stage 18 x 114 input tile (zero-padded at borders)
        const float* fc = fb + (size_t)ci * HH * WW;
        for (int i = tid; i < TROWS * TCOLS; i += 256) {
            const int r  = i / TCOLS;
            const int c  = i - r * TCOLS;
            const int gy = y0 - 1 + r;
            const int gx = c - 1;
            float v = 0.f;
            if (gy >= 0 && gy < HH && gx >= 0 && gx < WW) v = fc[gy * WW + gx];
            ts[i] = v;
        }
        __syncthreads();

        // neighborhood registers: 3 rows x 9 cols covering the 7-pixel strip
        float f[3][9];
        #pragma unroll
        for (int r = 0; r < 3; ++r)
            #pragma unroll
            for (int c = 0; c < 9; ++c)
                f[r][c] = ts[(ty + r) * TCOLS + tx * PX + c];

        #pragma unroll
        for (int o = 0; o < CO_PB; ++o) {
            #pragma unroll
            for (int kh = 0; kh < 3; ++kh) {
                #pragma unroll
                for (int kw = 0; kw < 3; ++kw) {
                    const float kv = ks[o * KSZ + ci * 9 + kh * 3 + kw];
                    #pragma unroll
                    for (int p = 0; p < PX; ++p)
                        acc[o][p] += kv * f[kh][p + kw];
                }
            }
        }
    }

    // epilogue: residual add + store
    const int y     = y0 + ty;
    const int xbase = tx * PX;
    #pragma unroll
    for (int o = 0; o < CO_PB; ++o) {
        const int co = cog * CO_PB + o;
        const float* fr = feat + (((size_t)b * CIN + co) * HH + y) * WW + xbase;
        float*       op = out  + (((size_t)b * COUT + co) * HH + y) * WW + xbase;
        #pragma unroll
        for (int p = 0; p < PX; ++p) op[p] = acc[o][p] + fr[p];
    }
}

extern "C" void kernel_launch(void* const* d_in, const int* in_sizes, int n_in,
                              void* d_out, int out_size, void* d_ws, size_t ws_size,
                              hipStream_t stream) {
    const float* cls      = (const float*)d_in[0];
    const float* features = (const float*)d_in[1];
    const float* W1       = (const float*)d_in[2];
    const float* b1       = (const float*)d_in[3];
    const float* W2       = (const float*)d_in[4];
    const float* b2       = (const float*)d_in[5];
    float* out = (float*)d_out;

    float* h      = (float*)d_ws;              // 16*192 floats
    float* params = h + BB * HID;              // 16*36864 floats

    mlp1_kernel<<<BB, HID, 0, stream>>>(cls, W1, b1, h);
    mlp2_kernel<<<TOTAL / 256, 256, 0, stream>>>(h, W2, b2, params);
    dim3 grid(7, 8, BB);
    conv_kernel<<<grid, 256, 0, stream>>>(features, params, out);
}

// Round 2
// 204.461 us; speedup vs baseline: 2.8766x; 2.8766x over previous
//
#include <hip/hip_runtime.h>
#include <hip/hip_bf16.h>

#define BB   16
#define EMB  768
#define CIN  64
#define COUT 64
#define HH   112
#define WW   112
#define HID  192
#define TOTAL 36864                 // COUT*CIN*9
#define KSZ  576                    // CIN*9

typedef short bf16x8 __attribute__((ext_vector_type(8)));
typedef float f32x4  __attribute__((ext_vector_type(4)));

static __device__ __forceinline__ unsigned short f2bf(float f) {
    unsigned u = __float_as_uint(f);
    u += 0x7FFF + ((u >> 16) & 1);          // RNE
    return (unsigned short)(u >> 16);
}

// ---------------- Kernel A: h = relu(cls @ W1 + b1)  (16 x 192) ----------------
__global__ void mlp1_kernel(const float* __restrict__ cls, const float* __restrict__ W1,
                            const float* __restrict__ b1, float* __restrict__ h) {
    __shared__ float xs[EMB];
    const int b = blockIdx.x;
    const int j = threadIdx.x;                 // 0..191
    for (int k = j; k < EMB; k += HID) xs[k] = cls[b * EMB + k];
    __syncthreads();
    float acc = b1[j];
    #pragma unroll 8
    for (int k = 0; k < EMB; ++k) acc += xs[k] * W1[k * HID + j];
    h[b * HID + j] = fmaxf(acc, 0.f);
}

// ---- Kernel B: params = tanh(h @ W2 + b2), written bf16 as A[b][p9][co][ci] ----
__global__ __launch_bounds__(256) void mlp2_kernel(const float* __restrict__ h,
                                                   const float* __restrict__ W2,
                                                   const float* __restrict__ b2,
                                                   unsigned short* __restrict__ Ag) {
    __shared__ float hs[BB * HID];
    const int tid = threadIdx.x;
    for (int i = tid; i < BB * HID; i += 256) hs[i] = h[i];
    __syncthreads();
    const int t = blockIdx.x * 256 + tid;      // 0..36863 (grid = 144 exact)
    float acc[BB];
    const float bias = b2[t];
    #pragma unroll
    for (int b = 0; b < BB; ++b) acc[b] = bias;
    for (int k = 0; k < HID; ++k) {
        const float w = W2[k * TOTAL + t];
        #pragma unroll
        for (int b = 0; b < BB; ++b) acc[b] += hs[b * HID + k] * w;
    }
    // t = co*576 + ci*9 + p9   ->   Ag[((b*9 + p9)*64 + co)*64 + ci]
    const int co  = t / KSZ;
    const int rem = t - co * KSZ;
    const int ci  = rem / 9;
    const int p9  = rem - ci * 9;
    #pragma unroll
    for (int b = 0; b < BB; ++b) {
        const size_t o = (((size_t)b * 9 + p9) * 64 + co) * 64 + ci;
        Ag[o] = f2bf(tanhf(acc[b]));
    }
}

// ---------------- Kernel C: MFMA implicit-GEMM conv + residual ----------------
// Block: 256 thr / 4 waves. Tile: all 64 co x 2 rows x 112 cols.
// LDS: bf16 transposed tile [4 rows][114 cols][64 ci], 16B-slice XOR swizzle.
#define ROWS  2
#define SROWS 4
#define SCOLS 114
#define CELL  128                   // bytes per (r,c) cell = 64 ci * 2B

__global__ __launch_bounds__(256) void conv_kernel(const float* __restrict__ feat,
                                                   const unsigned short* __restrict__ Ag,
                                                   float* __restrict__ out) {
    __shared__ char lds[SROWS * SCOLS * CELL];          // 58368 B
    const int tid = threadIdx.x;
    const int b   = blockIdx.y;
    const int y0  = blockIdx.x * ROWS;

    // ---- stage 4x114x64 halo tile, fp32 -> bf16, transposed [r][c][ci] ----
    const int cs   = tid & 127;                // LDS col 0..113 (x = cs-1)
    const int half = tid >> 7;                 // ci half 0/1
    if (cs < SCOLS) {
        const int  x  = cs - 1;
        const bool xv = (unsigned)x < WW;
        #pragma unroll
        for (int r = 0; r < SROWS; ++r) {
            const int  y  = y0 - 1 + r;
            const bool yv = (unsigned)y < HH;
            const float* fp = feat + (((size_t)b * CIN + half * 32) * HH + y) * WW + x;
            char* base = lds + (r * SCOLS + cs) * CELL;
            #pragma unroll
            for (int cc = 0; cc < 32; ++cc) {
                const int ci = half * 32 + cc;
                float v = (xv && yv) ? fp[(size_t)cc * HH * WW] : 0.f;
                const int slice = (ci >> 3) ^ (cs & 7);
                *(unsigned short*)(base + slice * 16 + (ci & 7) * 2) = f2bf(v);
            }
        }
    }
    __syncthreads();

    // ---- compute: wave = (co-half wc) x (out-row wp); 2 co-tiles x 7 px-tiles ----
    const int wave = tid >> 6;
    const int lane = tid & 63;
    const int wc   = wave & 1;
    const int wp   = wave >> 1;
    const int lg   = lane >> 4;                // 0..3
    const int ln   = lane & 15;

    f32x4 acc[2][7];
    #pragma unroll
    for (int ct = 0; ct < 2; ++ct)
        #pragma unroll
        for (int t = 0; t < 7; ++t)
            acc[ct][t] = (f32x4){0.f, 0.f, 0.f, 0.f};

    const unsigned short* Ab = Ag + (size_t)b * 9 * 64 * 64;

    #pragma unroll
    for (int p9 = 0; p9 < 9; ++p9) {
        const int kh = p9 / 3;
        const int kw = p9 - 3 * kh;
        // A-fragments: 2 co-tiles x 2 ci-blocks, 16B k-contiguous global loads
        bf16x8 af[2][2];
        #pragma unroll
        for (int ct = 0; ct < 2; ++ct)
            #pragma unroll
            for (int cib = 0; cib < 2; ++cib)
                af[ct][cib] = *(const bf16x8*)(Ab + ((size_t)(p9 * 64 + wc * 32 + ct * 16 + ln)) * 64
                                               + cib * 32 + lg * 8);
        const int rs  = wp + kh;               // staged row 0..3
        const int csx = ln + kw;               // LDS col for px-tile 0
        #pragma unroll
        for (int cib = 0; cib < 2; ++cib) {
            const int slice = (cib * 4 + lg) ^ (csx & 7);
            const char* bbase = lds + (rs * SCOLS + csx) * CELL + slice * 16;
            #pragma unroll
            for (int t = 0; t < 7; ++t) {
                bf16x8 bf = *(const bf16x8*)(bbase + t * 16 * CELL);
                acc[0][t] = __builtin_amdgcn_mfma_f32_16x16x32_bf16(af[0][cib], bf, acc[0][t], 0, 0, 0);
                acc[1][t] = __builtin_amdgcn_mfma_f32_16x16x32_bf16(af[1][cib], bf, acc[1][t], 0, 0, 0);
            }
        }
    }

    // ---- epilogue: D row=(lg*4+reg)=co_local, col=ln=px; residual add ----
    const int y = y0 + wp;
    #pragma unroll
    for (int ct = 0; ct < 2; ++ct) {
        #pragma unroll
        for (int t = 0; t < 7; ++t) {
            const int x = t * 16 + ln;
            #pragma unroll
            for (int rg = 0; rg < 4; ++rg) {
                const int co = wc * 32 + ct * 16 + lg * 4 + rg;
                const size_t o = (((size_t)b * COUT + co) * HH + y) * WW + x;
                out[o] = acc[ct][t][rg] + feat[o];
            }
        }
    }
}

extern "C" void kernel_launch(void* const* d_in, const int* in_sizes, int n_in,
                              void* d_out, int out_size, void* d_ws, size_t ws_size,
                              hipStream_t stream) {
    const float* cls      = (const float*)d_in[0];
    const float* features = (const float*)d_in[1];
    const float* W1       = (const float*)d_in[2];
    const float* b1       = (const float*)d_in[3];
    const float* W2       = (const float*)d_in[4];
    const float* b2       = (const float*)d_in[5];
    float* out = (float*)d_out;

    float*          h  = (float*)d_ws;                      // 16*192 f32
    unsigned short* Ag = (unsigned short*)(h + BB * HID);   // 16*9*64*64 bf16 (1.18 MB)

    mlp1_kernel<<<BB, HID, 0, stream>>>(cls, W1, b1, h);
    mlp2_kernel<<<TOTAL / 256, 256, 0, stream>>>(h, W2, b2, Ag);
    dim3 grid(HH / ROWS, BB);
    conv_kernel<<<grid, 256, 0, stream>>>(features, Ag, out);
}